// Round 4
// baseline (440.007 us; speedup 1.0000x reference)
//
#include <hip/hip_runtime.h>
#include <hip/hip_bf16.h>
#include <cstdint>

typedef __bf16 bf16_t;
typedef __bf16 bf16x8 __attribute__((ext_vector_type(8)));
typedef __bf16 bf16x4 __attribute__((ext_vector_type(4)));
typedef float f32x4 __attribute__((ext_vector_type(4)));

#define SEQ    1024
#define BATCH  8
#define NTOK   8192      // BATCH*SEQ
#define DMODEL 1024
#define NHEAD  16
#define HD     64
#define FFDIM  2048

// ---------------------------------------------------------------------------
// async global->LDS, 16B per lane. LDS dest is wave-uniform base + lane*16.
__device__ __forceinline__ void async16(const void* g, void* l) {
  __builtin_amdgcn_global_load_lds(
      (const __attribute__((address_space(1))) void*)g,
      (__attribute__((address_space(3))) void*)l, 16, 0, 0);
}

#define BARRIER() do { __builtin_amdgcn_s_barrier(); asm volatile("" ::: "memory"); } while (0)

// ---------------------------------------------------------------------------
__global__ __launch_bounds__(256)
void cast_bf16_kernel(const float* __restrict__ in, bf16_t* __restrict__ out, int n4) {
  int i = blockIdx.x * 256 + threadIdx.x;
  if (i >= n4) return;
  float4 v = ((const float4*)in)[i];
  bf16x4 o = { (bf16_t)v.x, (bf16_t)v.y, (bf16_t)v.z, (bf16_t)v.w };
  *(bf16x4*)&out[(size_t)i * 4] = o;
}

// ---------------------------------------------------------------------------
// transpose + cast: W fp32 [R][C] row-major -> Wt bf16 [C][R] row-major
__global__ __launch_bounds__(256)
void transpose_cast_kernel(const float* __restrict__ W, bf16_t* __restrict__ Wt,
                           int R, int C) {
  __shared__ float tile[32][33];
  const int bx = blockIdx.x * 32;
  const int by = blockIdx.y * 32;
  const int tx = threadIdx.x;
  const int ty = threadIdx.y;
#pragma unroll
  for (int i = 0; i < 4; ++i)
    tile[ty + 8 * i][tx] = W[(size_t)(by + ty + 8 * i) * C + bx + tx];
  __syncthreads();
#pragma unroll
  for (int i = 0; i < 4; ++i)
    Wt[(size_t)(bx + ty + 8 * i) * R + by + tx] = (bf16_t)tile[tx][ty + 8 * i];
}

// ---------------------------------------------------------------------------
// 256x256x(BK=64) bf16 GEMM, 4-quadrant-phase schedule with counted vmcnt.
// 512 threads = 8 waves (2M x 4N). Per-wave C: rows {q*128 + wm*64 + m*16},
// cols {pq*128 + wn*32 + n*16} over q,pq in {0,1}, m in 0..3, n in 0..1.
// LDS: 2 slots x (A 256x64 + B 256x64) = 128 KB, as 1KB subtiles [16r][32k].
// Staging lane geometry row=lane&15, col=(lane>>4)*8 makes every fragment
// ds_read exactly base+lane*16B -> conflict-free, no swizzle needed.
// Slot discipline: during tile tc only tile tc+1 (slot^1) is staged, one
// half-tile per phase in order A0,B0,B1,A1. Waits (before the barrier that
// publishes the NEXT phase's reads): vmcnt(4) at p1,p2,p4; prologue vmcnt(4);
// last tile vmcnt(2)/(0) at p1/p2. Max 2 half-tiles in flight.
// EPI: 0 = fp32 out (+bias if kz==0); 1 = bf16 relu; 2 = fused QKV epilogue.
template <int EPI>
__global__ __launch_bounds__(512)
void gemm256(const bf16_t* __restrict__ A, int lda,
             const bf16_t* __restrict__ Bt, int ldb,
             int K, int nTN, int nInner, int kOffA, int kOffB, size_t outStride,
             const float* __restrict__ bias0, const float* __restrict__ bias1,
             const float* __restrict__ bias2,
             void* __restrict__ o0, void* __restrict__ o1, void* __restrict__ o2,
             int ldo, float qscale) {
  __shared__ bf16_t As[2][16384];
  __shared__ bf16_t Bs[2][16384];
  const int tid = threadIdx.x;
  const int w = tid >> 6, l = tid & 63;
  const int fr = l & 15, ks = l >> 4;

  // bijective XCD swizzle (all grids are multiples of 8)
  const int nwg = gridDim.x, bid = blockIdx.x;
  int wg = (bid & 7) * (nwg >> 3) + (bid >> 3);
  const int kz = wg / nInner; wg -= kz * nInner;
  const int tm = wg / nTN, tn = wg - tm * nTN;
  const int bm = tm << 8, bn = tn << 8;
  A  += (size_t)kz * kOffA;
  Bt += (size_t)kz * kOffB;

  const int wm = w >> 2, wn = w & 3;

  // staging: wave w stages subtiles {w, w+8} of each 128-row half-tile.
  size_t aoff[2], boff[2];
  int ldsSub[2];
#pragma unroll
  for (int j = 0; j < 2; ++j) {
    const int sub = 8 * j + w, rtil = sub >> 1, ctil = sub & 1;
    aoff[j] = (size_t)(rtil * 16 + fr) * lda + ctil * 32 + ks * 8;
    boff[j] = (size_t)(rtil * 16 + fr) * ldb + ctil * 32 + ks * 8;
    ldsSub[j] = sub * 512;
  }

  f32x4 acc[8][4];
#pragma unroll
  for (int i = 0; i < 8; ++i)
#pragma unroll
    for (int j = 0; j < 4; ++j) acc[i][j] = (f32x4){0.f, 0.f, 0.f, 0.f};

  const int nk = K >> 6;
  const int totHT = nk << 2;   // half-tiles, order per tile: A0,B0,B1,A1
  int g = 0;

  auto issue_ht = [&](int gg) {
    const int tau = gg >> 2, ht = gg & 3;
    const int slot = tau & 1, h = ht >> 1;   // ht: 0=A0 1=B0 2=B1 3=A1
    if (ht == 0 || ht == 3) {
#pragma unroll
      for (int j = 0; j < 2; ++j)
        async16(A + (size_t)(bm + h * 128) * lda + (size_t)tau * 64 + aoff[j],
                &As[slot][h * 8192 + ldsSub[j]]);
    } else {
#pragma unroll
      for (int j = 0; j < 2; ++j)
        async16(Bt + (size_t)(bn + h * 128) * ldb + (size_t)tau * 64 + boff[j],
                &Bs[slot][h * 8192 + ldsSub[j]]);
    }
  };

  // prologue: tile 0's 4 half-tiles; A0,B0 must land before phase-1 reads.
  for (; g < 4; ++g) issue_ht(g);
  asm volatile("s_waitcnt vmcnt(4)" ::: "memory");
  BARRIER();

  bf16x8 afr[4][2], b0fr[2][2], b1fr[2][2];

  for (int tc = 0; tc < nk; ++tc) {
    const bool lastT = (tc == nk - 1);
    const bf16_t* Asl = As[tc & 1];
    const bf16_t* Bsl = Bs[tc & 1];

    // ---- phase 1: quadrant (A-half0, B-half0) ----
#pragma unroll
    for (int m = 0; m < 4; ++m)
#pragma unroll
      for (int kk = 0; kk < 2; ++kk)
        afr[m][kk] = *(const bf16x8*)&Asl[((wm * 4 + m) * 2 + kk) * 512 + l * 8];
#pragma unroll
    for (int n = 0; n < 2; ++n)
#pragma unroll
      for (int kk = 0; kk < 2; ++kk)
        b0fr[n][kk] = *(const bf16x8*)&Bsl[((wn * 2 + n) * 2 + kk) * 512 + l * 8];
    if (g < totHT) { issue_ht(g); ++g; }
    if (lastT) asm volatile("s_waitcnt vmcnt(2)" ::: "memory");  // covers B1(tc)
    else       asm volatile("s_waitcnt vmcnt(4)" ::: "memory");
    BARRIER();
    __builtin_amdgcn_s_setprio(1);
#pragma unroll
    for (int m = 0; m < 4; ++m)
#pragma unroll
      for (int n = 0; n < 2; ++n)
#pragma unroll
        for (int kk = 0; kk < 2; ++kk)
          acc[m][n] = __builtin_amdgcn_mfma_f32_16x16x32_bf16(afr[m][kk], b0fr[n][kk], acc[m][n], 0, 0, 0);
    __builtin_amdgcn_s_setprio(0);
    BARRIER();

    // ---- phase 2: (A-half0, B-half1) ----
#pragma unroll
    for (int n = 0; n < 2; ++n)
#pragma unroll
      for (int kk = 0; kk < 2; ++kk)
        b1fr[n][kk] = *(const bf16x8*)&Bsl[8192 + ((wn * 2 + n) * 2 + kk) * 512 + l * 8];
    if (g < totHT) { issue_ht(g); ++g; }
    if (lastT) asm volatile("s_waitcnt vmcnt(0)" ::: "memory");  // covers A1(tc)
    else       asm volatile("s_waitcnt vmcnt(4)" ::: "memory");
    BARRIER();
    __builtin_amdgcn_s_setprio(1);
#pragma unroll
    for (int m = 0; m < 4; ++m)
#pragma unroll
      for (int n = 0; n < 2; ++n)
#pragma unroll
        for (int kk = 0; kk < 2; ++kk)
          acc[m][2 + n] = __builtin_amdgcn_mfma_f32_16x16x32_bf16(afr[m][kk], b1fr[n][kk], acc[m][2 + n], 0, 0, 0);
    __builtin_amdgcn_s_setprio(0);
    BARRIER();

    // ---- phase 3: (A-half1, B-half1) ----
#pragma unroll
    for (int m = 0; m < 4; ++m)
#pragma unroll
      for (int kk = 0; kk < 2; ++kk)
        afr[m][kk] = *(const bf16x8*)&Asl[8192 + ((wm * 4 + m) * 2 + kk) * 512 + l * 8];
    if (g < totHT) { issue_ht(g); ++g; }
    BARRIER();
    __builtin_amdgcn_s_setprio(1);
#pragma unroll
    for (int m = 0; m < 4; ++m)
#pragma unroll
      for (int n = 0; n < 2; ++n)
#pragma unroll
        for (int kk = 0; kk < 2; ++kk)
          acc[4 + m][2 + n] = __builtin_amdgcn_mfma_f32_16x16x32_bf16(afr[m][kk], b1fr[n][kk], acc[4 + m][2 + n], 0, 0, 0);
    __builtin_amdgcn_s_setprio(0);
    BARRIER();

    // ---- phase 4: (A-half1, B-half0) ----
    if (g < totHT) { issue_ht(g); ++g; }
    if (!lastT) asm volatile("s_waitcnt vmcnt(4)" ::: "memory");  // covers A0,B0(tc+1)
    BARRIER();
    __builtin_amdgcn_s_setprio(1);
#pragma unroll
    for (int m = 0; m < 4; ++m)
#pragma unroll
      for (int n = 0; n < 2; ++n)
#pragma unroll
        for (int kk = 0; kk < 2; ++kk)
          acc[4 + m][n] = __builtin_amdgcn_mfma_f32_16x16x32_bf16(afr[m][kk], b0fr[n][kk], acc[4 + m][n], 0, 0, 0);
    __builtin_amdgcn_s_setprio(0);
    BARRIER();
  }

  // epilogue: C fragment (16x16): col = fr, row = ks*4 + r
  const int mode = bn >> 10;   // EPI 2: 0=Q 1=K 2=V (256-wide tiles don't straddle)
#pragma unroll
  for (int q = 0; q < 2; ++q)
#pragma unroll
    for (int m = 0; m < 4; ++m)
#pragma unroll
      for (int pq = 0; pq < 2; ++pq)
#pragma unroll
        for (int n = 0; n < 2; ++n) {
          const int mi = q * 4 + m, nj = pq * 2 + n;
          const int col = bn + pq * 128 + wn * 32 + n * 16 + fr;
          const int rowb = bm + q * 128 + wm * 64 + m * 16 + ks * 4;
#pragma unroll
          for (int r = 0; r < 4; ++r) {
            const int row = rowb + r;
            const float v = acc[mi][nj][r];
            if (EPI == 0) {
              const float bv = (kz == 0 && bias0) ? bias0[col] : 0.f;
              ((float*)o0)[kz * outStride + (size_t)row * ldo + col] = v + bv;
            } else if (EPI == 1) {
              ((bf16_t*)o0)[(size_t)row * ldo + col] = (bf16_t)fmaxf(v + bias0[col], 0.f);
            } else {
              const int cl = col & 1023;
              const int b_ = row >> 10, s_ = row & 1023, h_ = cl >> 6, e_ = cl & 63;
              if (mode == 0) {
                ((bf16_t*)o0)[((size_t)((b_ * NHEAD + h_) * SEQ + s_)) * HD + e_] =
                    (bf16_t)((v + bias0[cl]) * qscale);
              } else if (mode == 1) {
                ((bf16_t*)o1)[((size_t)((b_ * NHEAD + h_) * SEQ + s_)) * HD + e_] =
                    (bf16_t)(v + bias1[cl]);
              } else {
                ((bf16_t*)o2)[((size_t)((b_ * NHEAD + h_) * HD + e_)) * SEQ + s_] =
                    (bf16_t)(v + bias2[cl]);
              }
            }
          }
        }
}

// ---------------------------------------------------------------------------
// Flash attention (round-2 version, passing): swizzled K/V/P LDS, dbuf,
// exp2-domain defer-max softmax.
__global__ __launch_bounds__(256)
void attn_kernel(const bf16_t* __restrict__ Q, const bf16_t* __restrict__ K,
                 const bf16_t* __restrict__ VT, bf16_t* __restrict__ CTX) {
  const int bh = blockIdx.x;
  const int qt = blockIdx.y * 128;
  const int b_ = bh >> 4, h_ = bh & 15;
  const bf16_t* qh = Q + (size_t)bh * SEQ * HD;
  const bf16_t* kh = K + (size_t)bh * SEQ * HD;
  const bf16_t* vh = VT + (size_t)bh * HD * SEQ;
  const int tid = threadIdx.x, wave = tid >> 6, lane = tid & 63;
  const int fr = lane & 15, kg = (lane >> 4) * 8;
  const int lr = (lane >> 4) * 4, lc = lane & 15;

  __shared__ bf16_t Ks[2][64 * 64];
  __shared__ bf16_t Vs[2][64 * 64];
  __shared__ bf16_t Ps[128 * 64];

  const int srow = lane >> 3;
  const int scol = ((lane & 7) ^ srow) * 8;

  bf16x8 qf[2][2];
#pragma unroll
  for (int i = 0; i < 2; ++i)
#pragma unroll
    for (int kk = 0; kk < 2; ++kk)
      qf[i][kk] = *(const bf16x8*)&qh[(size_t)(qt + wave * 32 + i * 16 + fr) * HD + kk * 32 + kg];

  f32x4 octx[2][4];
  float mrun[2][4], lrun[2][4];
#pragma unroll
  for (int i = 0; i < 2; ++i)
#pragma unroll
    for (int j = 0; j < 4; ++j) octx[i][j] = (f32x4){0.f, 0.f, 0.f, 0.f};
#pragma unroll
  for (int i = 0; i < 2; ++i)
#pragma unroll
    for (int r = 0; r < 4; ++r) { mrun[i][r] = -1e30f; lrun[i][r] = 0.f; }

  auto stage = [&](int buf, int t) {
#pragma unroll
    for (int i = 0; i < 2; ++i) {
      const int ch = i * 4 + wave;
      const int row = ch * 8 + srow;
      async16(&kh[(size_t)(t * 64 + row) * HD + scol], &Ks[buf][ch * 512]);
      async16(&vh[(size_t)row * SEQ + t * 64 + scol], &Vs[buf][ch * 512]);
    }
  };

  stage(0, 0);
  asm volatile("s_waitcnt vmcnt(0)" ::: "memory");
  __syncthreads();

  for (int t = 0; t < SEQ / 64; ++t) {
    const int cur = t & 1;
    if (t + 1 < SEQ / 64) stage(cur ^ 1, t + 1);

    f32x4 sc[2][4];
#pragma unroll
    for (int i = 0; i < 2; ++i)
#pragma unroll
      for (int j = 0; j < 4; ++j) sc[i][j] = (f32x4){0.f, 0.f, 0.f, 0.f};
#pragma unroll
    for (int kk = 0; kk < 2; ++kk) {
      bf16x8 kf[4];
#pragma unroll
      for (int j = 0; j < 4; ++j) {
        const int row = j * 16 + fr;
        kf[j] = *(const bf16x8*)&Ks[cur][row * 64 + ((kk * 32 + kg) ^ ((row & 7) << 3))];
      }
#pragma unroll
      for (int i = 0; i < 2; ++i)
#pragma unroll
        for (int j = 0; j < 4; ++j)
          sc[i][j] = __builtin_amdgcn_mfma_f32_16x16x32_bf16(qf[i][kk], kf[j], sc[i][j], 0, 0, 0);
    }

    float pmx[2][4];
    int ok = 1;
#pragma unroll
    for (int i = 0; i < 2; ++i)
#pragma unroll
      for (int r = 0; r < 4; ++r) {
        const float m3 = fmaxf(fmaxf(sc[i][0][r], sc[i][1][r]),
                               fmaxf(sc[i][2][r], sc[i][3][r]));
        pmx[i][r] = m3;
        ok &= (m3 <= mrun[i][r] + 8.f) ? 1 : 0;
      }
    if (!__all(ok)) {
#pragma unroll
      for (int i = 0; i < 2; ++i)
#pragma unroll
        for (int r = 0; r < 4; ++r) {
          float mx = pmx[i][r];
#pragma unroll
          for (int m = 1; m < 16; m <<= 1) mx = fmaxf(mx, __shfl_xor(mx, m));
          const float mnew = fmaxf(mrun[i][r], mx);
          const float alpha = exp2f(mrun[i][r] - mnew);
          mrun[i][r] = mnew;
          lrun[i][r] *= alpha;
#pragma unroll
          for (int j = 0; j < 4; ++j) octx[i][j][r] *= alpha;
        }
    }
#pragma unroll
    for (int i = 0; i < 2; ++i)
#pragma unroll
      for (int r = 0; r < 4; ++r) {
        const float m = mrun[i][r];
        float s = 0.f;
#pragma unroll
        for (int j = 0; j < 4; ++j) {
          const float p = exp2f(sc[i][j][r] - m);
          sc[i][j][r] = p;
          s += p;
        }
        lrun[i][r] += s;
        const int prow = wave * 32 + i * 16 + lr + r;
#pragma unroll
        for (int j = 0; j < 4; ++j)
          Ps[prow * 64 + (((j * 16 + lc)) ^ ((prow & 7) << 3))] = (bf16_t)sc[i][j][r];
      }
    asm volatile("s_waitcnt lgkmcnt(0)" ::: "memory");

#pragma unroll
    for (int kk = 0; kk < 2; ++kk) {
      bf16x8 pf[2], vf[4];
#pragma unroll
      for (int i = 0; i < 2; ++i) {
        const int row = wave * 32 + i * 16 + fr;
        pf[i] = *(const bf16x8*)&Ps[row * 64 + ((kk * 32 + kg) ^ ((row & 7) << 3))];
      }
#pragma unroll
      for (int j = 0; j < 4; ++j) {
        const int row = j * 16 + fr;
        vf[j] = *(const bf16x8*)&Vs[cur][row * 64 + ((kk * 32 + kg) ^ ((row & 7) << 3))];
      }
#pragma unroll
      for (int i = 0; i < 2; ++i)
#pragma unroll
        for (int j = 0; j < 4; ++j)
          octx[i][j] = __builtin_amdgcn_mfma_f32_16x16x32_bf16(pf[i], vf[j], octx[i][j], 0, 0, 0);
    }

    asm volatile("s_waitcnt vmcnt(0)" ::: "memory");
    __syncthreads();
  }

#pragma unroll
  for (int i = 0; i < 2; ++i)
#pragma unroll
    for (int r = 0; r < 4; ++r) {
      float lsum = lrun[i][r];
#pragma unroll
      for (int m = 1; m < 16; m <<= 1) lsum += __shfl_xor(lsum, m);
      const float inv = 1.f / lsum;
      const int row = qt + wave * 32 + i * 16 + lr + r;
#pragma unroll
      for (int j = 0; j < 4; ++j) {
        const int c = j * 16 + lc;
        CTX[((size_t)(b_ * SEQ + row)) * DMODEL + h_ * HD + c] = (bf16_t)(octx[i][j][r] * inv);
      }
    }
}

// ---------------------------------------------------------------------------
// LN1: hb = bf16( LN(x + y0) * g + b )
__global__ __launch_bounds__(256)
void ln1_kernel(const float* __restrict__ X, const float* __restrict__ Y0,
                const float* __restrict__ g, const float* __restrict__ b,
                bf16_t* __restrict__ outb) {
  const int row = blockIdx.x, tid = threadIdx.x;
  const int wave = tid >> 6, lane = tid & 63;
  const float4 xv = ((const float4*)X)[(size_t)row * 256 + tid];
  const float4 yv = ((const float4*)Y0)[(size_t)row * 256 + tid];
  const float s0 = xv.x + yv.x, s1 = xv.y + yv.y, s2 = xv.z + yv.z, s3 = xv.w + yv.w;
  float sum = s0 + s1 + s2 + s3;
  float sq = s0 * s0 + s1 * s1 + s2 * s2 + s3 * s3;
#pragma unroll
  for (int off = 1; off < 64; off <<= 1) {
    sum += __shfl_xor(sum, off);
    sq += __shfl_xor(sq, off);
  }
  __shared__ float red[8];
  if (lane == 0) { red[wave] = sum; red[4 + wave] = sq; }
  __syncthreads();
  sum = red[0] + red[1] + red[2] + red[3];
  sq = red[4] + red[5] + red[6] + red[7];
  const float mu = sum * (1.f / 1024.f);
  const float var = sq * (1.f / 1024.f) - mu * mu;
  const float rstd = rsqrtf(var + 1e-5f);
  const float4 gv = ((const float4*)g)[tid];
  const float4 bv = ((const float4*)b)[tid];
  bf16x4 ob = { (bf16_t)((s0 - mu) * rstd * gv.x + bv.x),
                (bf16_t)((s1 - mu) * rstd * gv.y + bv.y),
                (bf16_t)((s2 - mu) * rstd * gv.z + bv.z),
                (bf16_t)((s3 - mu) * rstd * gv.w + bv.w) };
  *(bf16x4*)&outb[(size_t)row * 1024 + tid * 4] = ob;
}

// LN2: out = LN(hb + y0 + y1) * g + b
__global__ __launch_bounds__(256)
void ln2_kernel(const bf16_t* __restrict__ Hb, const float* __restrict__ Y0,
                const float* __restrict__ Y1, const float* __restrict__ g,
                const float* __restrict__ b, float* __restrict__ outf) {
  const int row = blockIdx.x, tid = threadIdx.x;
  const int wave = tid >> 6, lane = tid & 63;
  const bf16x4 hv = *(const bf16x4*)&Hb[(size_t)row * 1024 + tid * 4];
  const float4 y0 = ((const float4*)Y0)[(size_t)row * 256 + tid];
  const float4 y1 = ((const float4*)Y1)[(size_t)row * 256 + tid];
  const float s0 = (float)hv[0] + y0.x + y1.x, s1 = (float)hv[1] + y0.y + y1.y;
  const float s2 = (float)hv[2] + y0.z + y1.z, s3 = (float)hv[3] + y0.w + y1.w;
  float sum = s0 + s1 + s2 + s3;
  float sq = s0 * s0 + s1 * s1 + s2 * s2 + s3 * s3;
#pragma unroll
  for (int off = 1; off < 64; off <<= 1) {
    sum += __shfl_xor(sum, off);
    sq += __shfl_xor(sq, off);
  }
  __shared__ float red[8];
  if (lane == 0) { red[wave] = sum; red[4 + wave] = sq; }
  __syncthreads();
  sum = red[0] + red[1] + red[2] + red[3];
  sq = red[4] + red[5] + red[6] + red[7];
  const float mu = sum * (1.f / 1024.f);
  const float var = sq * (1.f / 1024.f) - mu * mu;
  const float rstd = rsqrtf(var + 1e-5f);
  const float4 gv = ((const float4*)g)[tid];
  const float4 bv = ((const float4*)b)[tid];
  ((float4*)outf)[(size_t)row * 256 + tid] =
      make_float4((s0 - mu) * rstd * gv.x + bv.x, (s1 - mu) * rstd * gv.y + bv.y,
                  (s2 - mu) * rstd * gv.z + bv.z, (s3 - mu) * rstd * gv.w + bv.w);
}

// ---------------------------------------------------------------------------
extern "C" void kernel_launch(void* const* d_in, const int* in_sizes, int n_in,
                              void* d_out, int out_size, void* d_ws, size_t ws_size,
                              hipStream_t stream) {
  const float* x   = (const float*)d_in[0];
  const float* Wq  = (const float*)d_in[1];
  const float* bq  = (const float*)d_in[2];
  const float* Wk  = (const float*)d_in[3];
  const float* bk  = (const float*)d_in[4];
  const float* Wv  = (const float*)d_in[5];
  const float* bv  = (const float*)d_in[6];
  const float* Wo  = (const float*)d_in[7];
  const float* bo  = (const float*)d_in[8];
  const float* g1  = (const float*)d_in[9];
  const float* be1 = (const float*)d_in[10];
  const float* W1  = (const float*)d_in[11];
  const float* b1  = (const float*)d_in[12];
  const float* W2  = (const float*)d_in[13];
  const float* b2  = (const float*)d_in[14];
  const float* g2  = (const float*)d_in[15];
  const float* be2 = (const float*)d_in[16];

  char* ws = (char*)d_ws;
  const size_t MB = 1u << 20;
  bf16_t* xb    = (bf16_t*)(ws + 0 * MB);     // 16 MB, x bf16 -> ctx after attn
  bf16_t* WqkvT = (bf16_t*)(ws + 16 * MB);    // 6 MB  [3072][1024]
  bf16_t* WoT   = (bf16_t*)(ws + 22 * MB);    // 2 MB
  bf16_t* W1T   = (bf16_t*)(ws + 24 * MB);    // 4 MB
  bf16_t* W2T   = (bf16_t*)(ws + 28 * MB);    // 4 MB
  bf16_t* qb    = (bf16_t*)(ws + 32 * MB);    // 16 MB -> hb after attn
  bf16_t* kb    = (bf16_t*)(ws + 48 * MB);    // 16 MB \ -> u (32MB) after attn
  bf16_t* vT    = (bf16_t*)(ws + 64 * MB);    // 16 MB /
  float*  y0    = (float*)(ws + 80 * MB);     // 32 MB fp32
  float*  y1    = (float*)(ws + 112 * MB);    // 32 MB fp32 (y0 + NTOK*1024)
  bf16_t* ctx = xb;
  bf16_t* hb  = qb;
  bf16_t* u   = kb;

  // prep
  cast_bf16_kernel<<<dim3(NTOK * DMODEL / 4 / 256), dim3(256), 0, stream>>>(x, xb, NTOK * DMODEL / 4);
  transpose_cast_kernel<<<dim3(32, 32), dim3(32, 8), 0, stream>>>(Wq, WqkvT, 1024, 1024);
  transpose_cast_kernel<<<dim3(32, 32), dim3(32, 8), 0, stream>>>(Wk, WqkvT + 1024 * 1024, 1024, 1024);
  transpose_cast_kernel<<<dim3(32, 32), dim3(32, 8), 0, stream>>>(Wv, WqkvT + 2 * 1024 * 1024, 1024, 1024);
  transpose_cast_kernel<<<dim3(32, 32), dim3(32, 8), 0, stream>>>(Wo, WoT, 1024, 1024);
  transpose_cast_kernel<<<dim3(64, 32), dim3(32, 8), 0, stream>>>(W1, W1T, 1024, 2048);
  transpose_cast_kernel<<<dim3(32, 64), dim3(32, 8), 0, stream>>>(W2, W2T, 2048, 1024);

  const float qscale = 0.125f * 1.44269504088896f;

  // fused QKV: M=8192, N=3072, K=1024 (grid 32x12 = 384)
  gemm256<2><<<dim3(384), dim3(512), 0, stream>>>(
      xb, 1024, WqkvT, 1024, 1024, 12, 384, 0, 0, 0,
      bq, bk, bv, qb, kb, vT, 0, qscale);

  // attention -> ctx (= xb)
  attn_kernel<<<dim3(128, 8), dim3(256), 0, stream>>>(qb, kb, vT, ctx);

  // Wo: M=8192, N=1024, K=1024 (grid 32x4 = 128) -> y0 fp32 (+bo)
  gemm256<0><<<dim3(128), dim3(512), 0, stream>>>(
      ctx, 1024, WoT, 1024, 1024, 4, 128, 0, 0, 0,
      bo, nullptr, nullptr, y0, nullptr, nullptr, 1024, 1.f);

  // LN1 -> hb (bf16)
  ln1_kernel<<<dim3(NTOK), dim3(256), 0, stream>>>(x, y0, g1, be1, hb);

  // FFN1: M=8192, N=2048, K=1024 (grid 32x8 = 256) -> u bf16 relu
  gemm256<1><<<dim3(256), dim3(512), 0, stream>>>(
      hb, 1024, W1T, 1024, 1024, 8, 256, 0, 0, 0,
      b1, nullptr, nullptr, u, nullptr, nullptr, 2048, 1.f);

  // FFN2 split-K: 2 x (M=8192, N=1024, K=1024) -> y0, y1 fp32
  gemm256<0><<<dim3(256), dim3(512), 0, stream>>>(
      u, 2048, W2T, 2048, 1024, 4, 128, 1024, 1024, (size_t)NTOK * 1024,
      b2, nullptr, nullptr, y0, nullptr, nullptr, 1024, 1.f);

  // LN2 -> d_out
  ln2_kernel<<<dim3(NTOK), dim3(256), 0, stream>>>(hb, y0, y1, g2, be2, (float*)d_out);
}

// Round 5
// 425.524 us; speedup vs baseline: 1.0340x; 1.0340x over previous
//
#include <hip/hip_runtime.h>
#include <hip/hip_bf16.h>
#include <cstdint>

typedef __bf16 bf16_t;
typedef __bf16 bf16x8 __attribute__((ext_vector_type(8)));
typedef __bf16 bf16x4 __attribute__((ext_vector_type(4)));
typedef float f32x4 __attribute__((ext_vector_type(4)));

#define SEQ    1024
#define BATCH  8
#define NTOK   8192      // BATCH*SEQ
#define DMODEL 1024
#define NHEAD  16
#define HD     64
#define FFDIM  2048

// ---------------------------------------------------------------------------
// async global->LDS, 16B per lane. LDS dest is wave-uniform base + lane*16.
__device__ __forceinline__ void async16(const void* g, void* l) {
  __builtin_amdgcn_global_load_lds(
      (const __attribute__((address_space(1))) void*)g,
      (__attribute__((address_space(3))) void*)l, 16, 0, 0);
}

#define BARRIER() do { __builtin_amdgcn_s_barrier(); asm volatile("" ::: "memory"); } while (0)
#define WAITV(n)  asm volatile("s_waitcnt vmcnt(" #n ")" ::: "memory")

// ---------------------------------------------------------------------------
__global__ __launch_bounds__(256)
void cast_bf16_kernel(const float* __restrict__ in, bf16_t* __restrict__ out, int n4) {
  int i = blockIdx.x * 256 + threadIdx.x;
  if (i >= n4) return;
  float4 v = ((const float4*)in)[i];
  bf16x4 o = { (bf16_t)v.x, (bf16_t)v.y, (bf16_t)v.z, (bf16_t)v.w };
  *(bf16x4*)&out[(size_t)i * 4] = o;
}

// ---------------------------------------------------------------------------
// transpose + cast: W fp32 [R][C] row-major -> Wt bf16 [C][R] row-major
__global__ __launch_bounds__(256)
void transpose_cast_kernel(const float* __restrict__ W, bf16_t* __restrict__ Wt,
                           int R, int C) {
  __shared__ float tile[32][33];
  const int bx = blockIdx.x * 32;
  const int by = blockIdx.y * 32;
  const int tx = threadIdx.x;
  const int ty = threadIdx.y;
#pragma unroll
  for (int i = 0; i < 4; ++i)
    tile[ty + 8 * i][tx] = W[(size_t)(by + ty + 8 * i) * C + bx + tx];
  __syncthreads();
#pragma unroll
  for (int i = 0; i < 4; ++i)
    Wt[(size_t)(bx + ty + 8 * i) * R + by + tx] = (bf16_t)tile[tx][ty + 8 * i];
}

// ---------------------------------------------------------------------------
// 256x256x(BK=64) bf16 GEMM, deep-pipelined 8-phase schedule.
// 512 threads = 8 waves (2M x 4N). Even K-tiles -> LDS slot0, odd -> slot1.
// Per K-tile, 4 quadrant phases: q1=(A0,B0) q2=(A0,B1) q3=(A1,B1) q4=(A1,B0);
// fragment regs are reused across phases so each LDS quadrant is DEAD right
// after its phase's ds_reads. Staging for tile T+2 is issued into the freed
// quadrant of the same slot, one half-tile per phase, order
// p1:A1(T1) p2:A0(T2) p3:B0(T2) p4:B1(T2) p5:A1(T2) p6:A0(T3) p7:B0(T3)
// p8:B1(T3) -> prefetch distance 6-7 phases (covers ~900cy HBM latency).
// Counted waits (cover the NEXT phase's reads, before the pre-MFMA barrier):
// steady vmcnt(10) at p1,p2,p4,p5,p6,p8; final-iteration tail 10/8/-/4/2/0/-/-.
// Ledger verified: at each wait the needed half-tile is the oldest beyond the
// allowed count, for prologue, steady state, and tail.
// EPI: 0 = fp32 out (+bias if kz==0); 1 = bf16 relu; 2 = fused QKV epilogue.
template <int EPI>
__global__ __launch_bounds__(512)
void gemm256(const bf16_t* __restrict__ A, int lda,
             const bf16_t* __restrict__ Bt, int ldb,
             int K, int nTN, int nInner, int kOffA, int kOffB, size_t outStride,
             const float* __restrict__ bias0, const float* __restrict__ bias1,
             const float* __restrict__ bias2,
             void* __restrict__ o0, void* __restrict__ o1, void* __restrict__ o2,
             int ldo, float qscale) {
  __shared__ bf16_t As[2][16384];
  __shared__ bf16_t Bs[2][16384];
  const int tid = threadIdx.x;
  const int w = tid >> 6, l = tid & 63;
  const int fr = l & 15, ks = l >> 4;

  // bijective XCD swizzle (all grids are multiples of 8)
  const int nwg = gridDim.x, bid = blockIdx.x;
  int wg = (bid & 7) * (nwg >> 3) + (bid >> 3);
  const int kz = wg / nInner; wg -= kz * nInner;
  const int tm = wg / nTN, tn = wg - tm * nTN;
  const int bm = tm << 8, bn = tn << 8;
  A  += (size_t)kz * kOffA;
  Bt += (size_t)kz * kOffB;

  const int wm = w >> 2, wn = w & 3;

  // staging: wave w stages subtiles {w, w+8} of each 128-row half-tile;
  // per-lane global src (row fr, k-chunk ks) matches linear LDS dest
  // base+lane*16B, so fragment ds_reads are base+lane*16B (conflict-free).
  size_t aoff[2], boff[2];
  int ldsSub[2];
#pragma unroll
  for (int j = 0; j < 2; ++j) {
    const int sub = 8 * j + w, rtil = sub >> 1, ctil = sub & 1;
    aoff[j] = (size_t)(rtil * 16 + fr) * lda + ctil * 32 + ks * 8;
    boff[j] = (size_t)(rtil * 16 + fr) * ldb + ctil * 32 + ks * 8;
    ldsSub[j] = sub * 512;
  }

  auto issueA = [&](int t, int h) {
#pragma unroll
    for (int j = 0; j < 2; ++j)
      async16(A + (size_t)(bm + h * 128) * lda + (size_t)t * 64 + aoff[j],
              &As[t & 1][h * 8192 + ldsSub[j]]);
  };
  auto issueB = [&](int t, int h) {
#pragma unroll
    for (int j = 0; j < 2; ++j)
      async16(Bt + (size_t)(bn + h * 128) * ldb + (size_t)t * 64 + boff[j],
              &Bs[t & 1][h * 8192 + ldsSub[j]]);
  };

  f32x4 acc[8][4];
#pragma unroll
  for (int i = 0; i < 8; ++i)
#pragma unroll
    for (int j = 0; j < 4; ++j) acc[i][j] = (f32x4){0.f, 0.f, 0.f, 0.f};

  bf16x8 afr[4][2], b0fr[2][2], b1fr[2][2];

#define READ_A(slot, half)                                                       \
  do {                                                                           \
    _Pragma("unroll") for (int m = 0; m < 4; ++m)                                \
      _Pragma("unroll") for (int kk = 0; kk < 2; ++kk)                           \
        afr[m][kk] = *(const bf16x8*)&As[slot][(half) * 8192 +                   \
                        ((wm * 4 + m) * 2 + kk) * 512 + l * 8];                  \
  } while (0)
#define READ_B(slot, half, dst)                                                  \
  do {                                                                           \
    _Pragma("unroll") for (int n = 0; n < 2; ++n)                                \
      _Pragma("unroll") for (int kk = 0; kk < 2; ++kk)                           \
        dst[n][kk] = *(const bf16x8*)&Bs[slot][(half) * 8192 +                   \
                        ((wn * 2 + n) * 2 + kk) * 512 + l * 8];                  \
  } while (0)
#define MFMA_Q(ah, bh, bsrc)                                                     \
  do {                                                                           \
    __builtin_amdgcn_s_setprio(1);                                               \
    _Pragma("unroll") for (int m = 0; m < 4; ++m)                                \
      _Pragma("unroll") for (int n = 0; n < 2; ++n)                              \
        _Pragma("unroll") for (int kk = 0; kk < 2; ++kk)                         \
          acc[(ah) * 4 + m][(bh) * 2 + n] = __builtin_amdgcn_mfma_f32_16x16x32_bf16( \
              afr[m][kk], bsrc[n][kk], acc[(ah) * 4 + m][(bh) * 2 + n], 0, 0, 0);\
    __builtin_amdgcn_s_setprio(0);                                               \
  } while (0)

  const int nk = K >> 6;          // even (>=8) for all our shapes
  const int nIter = nk >> 1;

  // prologue: tile0 {A0,B0,B1,A1}, tile1 {A0,B0,B1} = 7 half-tiles
  issueA(0, 0); issueB(0, 0); issueB(0, 1); issueA(0, 1);
  issueA(1, 0); issueB(1, 0); issueB(1, 1);
  WAITV(10);                      // A0(0),B0(0) landed
  BARRIER();

  for (int it = 0; it < nIter; ++it) {
    const int T1 = 2 * it + 1, T2 = 2 * it + 2, T3 = 2 * it + 3;
    const bool more = (T2 < nk);

    // ---- p1: slot0 q1 ----
    READ_A(0, 0); READ_B(0, 0, b0fr);
    issueA(T1, 1);
    WAITV(10);
    BARRIER(); MFMA_Q(0, 0, b0fr); BARRIER();
    // ---- p2: slot0 q2 ----
    READ_B(0, 1, b1fr);
    if (more) { issueA(T2, 0); WAITV(10); } else { WAITV(8); }
    BARRIER(); MFMA_Q(0, 1, b1fr); BARRIER();
    // ---- p3: slot0 q3 ----
    READ_A(0, 1);
    if (more) issueB(T2, 0);
    BARRIER(); MFMA_Q(1, 1, b1fr); BARRIER();
    // ---- p4: slot0 q4 ----
    if (more) { issueB(T2, 1); WAITV(10); } else { WAITV(4); }
    BARRIER(); MFMA_Q(1, 0, b0fr); BARRIER();
    // ---- p5: slot1 q1 ----
    READ_A(1, 0); READ_B(1, 0, b0fr);
    if (more) { issueA(T2, 1); WAITV(10); } else { WAITV(2); }
    BARRIER(); MFMA_Q(0, 0, b0fr); BARRIER();
    // ---- p6: slot1 q2 ----
    READ_B(1, 1, b1fr);
    if (more) { issueA(T3, 0); WAITV(10); } else { WAITV(0); }
    BARRIER(); MFMA_Q(0, 1, b1fr); BARRIER();
    // ---- p7: slot1 q3 ----
    READ_A(1, 1);
    if (more) issueB(T3, 0);
    BARRIER(); MFMA_Q(1, 1, b1fr); BARRIER();
    // ---- p8: slot1 q4 ----
    if (more) { issueB(T3, 1); WAITV(10); }
    BARRIER(); MFMA_Q(1, 0, b0fr); BARRIER();
  }
#undef READ_A
#undef READ_B
#undef MFMA_Q

  // epilogue: C fragment (16x16): col = fr, row = ks*4 + r
  const int mode = bn >> 10;   // EPI 2: 0=Q 1=K 2=V (256-wide tiles don't straddle)
#pragma unroll
  for (int q = 0; q < 2; ++q)
#pragma unroll
    for (int m = 0; m < 4; ++m)
#pragma unroll
      for (int pq = 0; pq < 2; ++pq)
#pragma unroll
        for (int n = 0; n < 2; ++n) {
          const int mi = q * 4 + m, nj = pq * 2 + n;
          const int col = bn + pq * 128 + wn * 32 + n * 16 + fr;
          const int rowb = bm + q * 128 + wm * 64 + m * 16 + ks * 4;
#pragma unroll
          for (int r = 0; r < 4; ++r) {
            const int row = rowb + r;
            const float v = acc[mi][nj][r];
            if (EPI == 0) {
              const float bv = (kz == 0 && bias0) ? bias0[col] : 0.f;
              ((float*)o0)[kz * outStride + (size_t)row * ldo + col] = v + bv;
            } else if (EPI == 1) {
              ((bf16_t*)o0)[(size_t)row * ldo + col] = (bf16_t)fmaxf(v + bias0[col], 0.f);
            } else {
              const int cl = col & 1023;
              const int b_ = row >> 10, s_ = row & 1023, h_ = cl >> 6, e_ = cl & 63;
              if (mode == 0) {
                ((bf16_t*)o0)[((size_t)((b_ * NHEAD + h_) * SEQ + s_)) * HD + e_] =
                    (bf16_t)((v + bias0[cl]) * qscale);
              } else if (mode == 1) {
                ((bf16_t*)o1)[((size_t)((b_ * NHEAD + h_) * SEQ + s_)) * HD + e_] =
                    (bf16_t)(v + bias1[cl]);
              } else {
                ((bf16_t*)o2)[((size_t)((b_ * NHEAD + h_) * HD + e_)) * SEQ + s_] =
                    (bf16_t)(v + bias2[cl]);
              }
            }
          }
        }
}

// ---------------------------------------------------------------------------
// Flash attention (round-2 version, passing): swizzled K/V/P LDS, dbuf,
// exp2-domain defer-max softmax.
__global__ __launch_bounds__(256)
void attn_kernel(const bf16_t* __restrict__ Q, const bf16_t* __restrict__ K,
                 const bf16_t* __restrict__ VT, bf16_t* __restrict__ CTX) {
  const int bh = blockIdx.x;
  const int qt = blockIdx.y * 128;
  const int b_ = bh >> 4, h_ = bh & 15;
  const bf16_t* qh = Q + (size_t)bh * SEQ * HD;
  const bf16_t* kh = K + (size_t)bh * SEQ * HD;
  const bf16_t* vh = VT + (size_t)bh * HD * SEQ;
  const int tid = threadIdx.x, wave = tid >> 6, lane = tid & 63;
  const int fr = lane & 15, kg = (lane >> 4) * 8;
  const int lr = (lane >> 4) * 4, lc = lane & 15;

  __shared__ bf16_t Ks[2][64 * 64];
  __shared__ bf16_t Vs[2][64 * 64];
  __shared__ bf16_t Ps[128 * 64];

  const int srow = lane >> 3;
  const int scol = ((lane & 7) ^ srow) * 8;

  bf16x8 qf[2][2];
#pragma unroll
  for (int i = 0; i < 2; ++i)
#pragma unroll
    for (int kk = 0; kk < 2; ++kk)
      qf[i][kk] = *(const bf16x8*)&qh[(size_t)(qt + wave * 32 + i * 16 + fr) * HD + kk * 32 + kg];

  f32x4 octx[2][4];
  float mrun[2][4], lrun[2][4];
#pragma unroll
  for (int i = 0; i < 2; ++i)
#pragma unroll
    for (int j = 0; j < 4; ++j) octx[i][j] = (f32x4){0.f, 0.f, 0.f, 0.f};
#pragma unroll
  for (int i = 0; i < 2; ++i)
#pragma unroll
    for (int r = 0; r < 4; ++r) { mrun[i][r] = -1e30f; lrun[i][r] = 0.f; }

  auto stage = [&](int buf, int t) {
#pragma unroll
    for (int i = 0; i < 2; ++i) {
      const int ch = i * 4 + wave;
      const int row = ch * 8 + srow;
      async16(&kh[(size_t)(t * 64 + row) * HD + scol], &Ks[buf][ch * 512]);
      async16(&vh[(size_t)row * SEQ + t * 64 + scol], &Vs[buf][ch * 512]);
    }
  };

  stage(0, 0);
  asm volatile("s_waitcnt vmcnt(0)" ::: "memory");
  __syncthreads();

  for (int t = 0; t < SEQ / 64; ++t) {
    const int cur = t & 1;
    if (t + 1 < SEQ / 64) stage(cur ^ 1, t + 1);

    f32x4 sc[2][4];
#pragma unroll
    for (int i = 0; i < 2; ++i)
#pragma unroll
      for (int j = 0; j < 4; ++j) sc[i][j] = (f32x4){0.f, 0.f, 0.f, 0.f};
#pragma unroll
    for (int kk = 0; kk < 2; ++kk) {
      bf16x8 kf[4];
#pragma unroll
      for (int j = 0; j < 4; ++j) {
        const int row = j * 16 + fr;
        kf[j] = *(const bf16x8*)&Ks[cur][row * 64 + ((kk * 32 + kg) ^ ((row & 7) << 3))];
      }
#pragma unroll
      for (int i = 0; i < 2; ++i)
#pragma unroll
        for (int j = 0; j < 4; ++j)
          sc[i][j] = __builtin_amdgcn_mfma_f32_16x16x32_bf16(qf[i][kk], kf[j], sc[i][j], 0, 0, 0);
    }

    float pmx[2][4];
    int ok = 1;
#pragma unroll
    for (int i = 0; i < 2; ++i)
#pragma unroll
      for (int r = 0; r < 4; ++r) {
        const float m3 = fmaxf(fmaxf(sc[i][0][r], sc[i][1][r]),
                               fmaxf(sc[i][2][r], sc[i][3][r]));
        pmx[i][r] = m3;
        ok &= (m3 <= mrun[i][r] + 8.f) ? 1 : 0;
      }
    if (!__all(ok)) {
#pragma unroll
      for (int i = 0; i < 2; ++i)
#pragma unroll
        for (int r = 0; r < 4; ++r) {
          float mx = pmx[i][r];
#pragma unroll
          for (int m = 1; m < 16; m <<= 1) mx = fmaxf(mx, __shfl_xor(mx, m));
          const float mnew = fmaxf(mrun[i][r], mx);
          const float alpha = exp2f(mrun[i][r] - mnew);
          mrun[i][r] = mnew;
          lrun[i][r] *= alpha;
#pragma unroll
          for (int j = 0; j < 4; ++j) octx[i][j][r] *= alpha;
        }
    }
#pragma unroll
    for (int i = 0; i < 2; ++i)
#pragma unroll
      for (int r = 0; r < 4; ++r) {
        const float m = mrun[i][r];
        float s = 0.f;
#pragma unroll
        for (int j = 0; j < 4; ++j) {
          const float p = exp2f(sc[i][j][r] - m);
          sc[i][j][r] = p;
          s += p;
        }
        lrun[i][r] += s;
        const int prow = wave * 32 + i * 16 + lr + r;
#pragma unroll
        for (int j = 0; j < 4; ++j)
          Ps[prow * 64 + (((j * 16 + lc)) ^ ((prow & 7) << 3))] = (bf16_t)sc[i][j][r];
      }
    asm volatile("s_waitcnt lgkmcnt(0)" ::: "memory");

#pragma unroll
    for (int kk = 0; kk < 2; ++kk) {
      bf16x8 pf[2], vf[4];
#pragma unroll
      for (int i = 0; i < 2; ++i) {
        const int row = wave * 32 + i * 16 + fr;
        pf[i] = *(const bf16x8*)&Ps[row * 64 + ((kk * 32 + kg) ^ ((row & 7) << 3))];
      }
#pragma unroll
      for (int j = 0; j < 4; ++j) {
        const int row = j * 16 + fr;
        vf[j] = *(const bf16x8*)&Vs[cur][row * 64 + ((kk * 32 + kg) ^ ((row & 7) << 3))];
      }
#pragma unroll
      for (int i = 0; i < 2; ++i)
#pragma unroll
        for (int j = 0; j < 4; ++j)
          octx[i][j] = __builtin_amdgcn_mfma_f32_16x16x32_bf16(pf[i], vf[j], octx[i][j], 0, 0, 0);
    }

    asm volatile("s_waitcnt vmcnt(0)" ::: "memory");
    __syncthreads();
  }

#pragma unroll
  for (int i = 0; i < 2; ++i)
#pragma unroll
    for (int r = 0; r < 4; ++r) {
      float lsum = lrun[i][r];
#pragma unroll
      for (int m = 1; m < 16; m <<= 1) lsum += __shfl_xor(lsum, m);
      const float inv = 1.f / lsum;
      const int row = qt + wave * 32 + i * 16 + lr + r;
#pragma unroll
      for (int j = 0; j < 4; ++j) {
        const int c = j * 16 + lc;
        CTX[((size_t)(b_ * SEQ + row)) * DMODEL + h_ * HD + c] = (bf16_t)(octx[i][j][r] * inv);
      }
    }
}

// ---------------------------------------------------------------------------
// LN1: hb = bf16( LN(x + y0 + y1) * g + b )   (y0,y1 = Wo split-K partials)
__global__ __launch_bounds__(256)
void ln1_kernel(const float* __restrict__ X, const float* __restrict__ Y0,
                const float* __restrict__ Y1, const float* __restrict__ g,
                const float* __restrict__ b, bf16_t* __restrict__ outb) {
  const int row = blockIdx.x, tid = threadIdx.x;
  const int wave = tid >> 6, lane = tid & 63;
  const float4 xv = ((const float4*)X)[(size_t)row * 256 + tid];
  const float4 y0 = ((const float4*)Y0)[(size_t)row * 256 + tid];
  const float4 y1 = ((const float4*)Y1)[(size_t)row * 256 + tid];
  const float s0 = xv.x + y0.x + y1.x, s1 = xv.y + y0.y + y1.y;
  const float s2 = xv.z + y0.z + y1.z, s3 = xv.w + y0.w + y1.w;
  float sum = s0 + s1 + s2 + s3;
  float sq = s0 * s0 + s1 * s1 + s2 * s2 + s3 * s3;
#pragma unroll
  for (int off = 1; off < 64; off <<= 1) {
    sum += __shfl_xor(sum, off);
    sq += __shfl_xor(sq, off);
  }
  __shared__ float red[8];
  if (lane == 0) { red[wave] = sum; red[4 + wave] = sq; }
  __syncthreads();
  sum = red[0] + red[1] + red[2] + red[3];
  sq = red[4] + red[5] + red[6] + red[7];
  const float mu = sum * (1.f / 1024.f);
  const float var = sq * (1.f / 1024.f) - mu * mu;
  const float rstd = rsqrtf(var + 1e-5f);
  const float4 gv = ((const float4*)g)[tid];
  const float4 bv = ((const float4*)b)[tid];
  bf16x4 ob = { (bf16_t)((s0 - mu) * rstd * gv.x + bv.x),
                (bf16_t)((s1 - mu) * rstd * gv.y + bv.y),
                (bf16_t)((s2 - mu) * rstd * gv.z + bv.z),
                (bf16_t)((s3 - mu) * rstd * gv.w + bv.w) };
  *(bf16x4*)&outb[(size_t)row * 1024 + tid * 4] = ob;
}

// LN2: out = LN(hb + y0 + y1) * g + b
__global__ __launch_bounds__(256)
void ln2_kernel(const bf16_t* __restrict__ Hb, const float* __restrict__ Y0,
                const float* __restrict__ Y1, const float* __restrict__ g,
                const float* __restrict__ b, float* __restrict__ outf) {
  const int row = blockIdx.x, tid = threadIdx.x;
  const int wave = tid >> 6, lane = tid & 63;
  const bf16x4 hv = *(const bf16x4*)&Hb[(size_t)row * 1024 + tid * 4];
  const float4 y0 = ((const float4*)Y0)[(size_t)row * 256 + tid];
  const float4 y1 = ((const float4*)Y1)[(size_t)row * 256 + tid];
  const float s0 = (float)hv[0] + y0.x + y1.x, s1 = (float)hv[1] + y0.y + y1.y;
  const float s2 = (float)hv[2] + y0.z + y1.z, s3 = (float)hv[3] + y0.w + y1.w;
  float sum = s0 + s1 + s2 + s3;
  float sq = s0 * s0 + s1 * s1 + s2 * s2 + s3 * s3;
#pragma unroll
  for (int off = 1; off < 64; off <<= 1) {
    sum += __shfl_xor(sum, off);
    sq += __shfl_xor(sq, off);
  }
  __shared__ float red[8];
  if (lane == 0) { red[wave] = sum; red[4 + wave] = sq; }
  __syncthreads();
  sum = red[0] + red[1] + red[2] + red[3];
  sq = red[4] + red[5] + red[6] + red[7];
  const float mu = sum * (1.f / 1024.f);
  const float var = sq * (1.f / 1024.f) - mu * mu;
  const float rstd = rsqrtf(var + 1e-5f);
  const float4 gv = ((const float4*)g)[tid];
  const float4 bv = ((const float4*)b)[tid];
  ((float4*)outf)[(size_t)row * 256 + tid] =
      make_float4((s0 - mu) * rstd * gv.x + bv.x, (s1 - mu) * rstd * gv.y + bv.y,
                  (s2 - mu) * rstd * gv.z + bv.z, (s3 - mu) * rstd * gv.w + bv.w);
}

// ---------------------------------------------------------------------------
extern "C" void kernel_launch(void* const* d_in, const int* in_sizes, int n_in,
                              void* d_out, int out_size, void* d_ws, size_t ws_size,
                              hipStream_t stream) {
  const float* x   = (const float*)d_in[0];
  const float* Wq  = (const float*)d_in[1];
  const float* bq  = (const float*)d_in[2];
  const float* Wk  = (const float*)d_in[3];
  const float* bk  = (const float*)d_in[4];
  const float* Wv  = (const float*)d_in[5];
  const float* bv  = (const float*)d_in[6];
  const float* Wo  = (const float*)d_in[7];
  const float* bo  = (const float*)d_in[8];
  const float* g1  = (const float*)d_in[9];
  const float* be1 = (const float*)d_in[10];
  const float* W1  = (const float*)d_in[11];
  const float* b1  = (const float*)d_in[12];
  const float* W2  = (const float*)d_in[13];
  const float* b2  = (const float*)d_in[14];
  const float* g2  = (const float*)d_in[15];
  const float* be2 = (const float*)d_in[16];

  char* ws = (char*)d_ws;
  const size_t MB = 1u << 20;
  bf16_t* xb    = (bf16_t*)(ws + 0 * MB);     // 16 MB, x bf16 -> ctx after attn
  bf16_t* WqkvT = (bf16_t*)(ws + 16 * MB);    // 6 MB  [3072][1024]
  bf16_t* WoT   = (bf16_t*)(ws + 22 * MB);    // 2 MB
  bf16_t* W1T   = (bf16_t*)(ws + 24 * MB);    // 4 MB
  bf16_t* W2T   = (bf16_t*)(ws + 28 * MB);    // 4 MB
  bf16_t* qb    = (bf16_t*)(ws + 32 * MB);    // 16 MB -> hb after attn
  bf16_t* kb    = (bf16_t*)(ws + 48 * MB);    // 16 MB \ -> u (32MB) after attn
  bf16_t* vT    = (bf16_t*)(ws + 64 * MB);    // 16 MB /
  float*  y0    = (float*)(ws + 80 * MB);     // 32 MB fp32
  float*  y1    = (float*)(ws + 112 * MB);    // 32 MB fp32 (y0 + NTOK*1024)
  bf16_t* ctx = xb;
  bf16_t* hb  = qb;
  bf16_t* u   = kb;

  // prep
  cast_bf16_kernel<<<dim3(NTOK * DMODEL / 4 / 256), dim3(256), 0, stream>>>(x, xb, NTOK * DMODEL / 4);
  transpose_cast_kernel<<<dim3(32, 32), dim3(32, 8), 0, stream>>>(Wq, WqkvT, 1024, 1024);
  transpose_cast_kernel<<<dim3(32, 32), dim3(32, 8), 0, stream>>>(Wk, WqkvT + 1024 * 1024, 1024, 1024);
  transpose_cast_kernel<<<dim3(32, 32), dim3(32, 8), 0, stream>>>(Wv, WqkvT + 2 * 1024 * 1024, 1024, 1024);
  transpose_cast_kernel<<<dim3(32, 32), dim3(32, 8), 0, stream>>>(Wo, WoT, 1024, 1024);
  transpose_cast_kernel<<<dim3(64, 32), dim3(32, 8), 0, stream>>>(W1, W1T, 1024, 2048);
  transpose_cast_kernel<<<dim3(32, 64), dim3(32, 8), 0, stream>>>(W2, W2T, 2048, 1024);

  const float qscale = 0.125f * 1.44269504088896f;

  // fused QKV: M=8192, N=3072, K=1024 (grid 32x12 = 384)
  gemm256<2><<<dim3(384), dim3(512), 0, stream>>>(
      xb, 1024, WqkvT, 1024, 1024, 12, 384, 0, 0, 0,
      bq, bk, bv, qb, kb, vT, 0, qscale);

  // attention -> ctx (= xb)
  attn_kernel<<<dim3(128, 8), dim3(256), 0, stream>>>(qb, kb, vT, ctx);

  // Wo split-K: 2 x (M=8192, N=1024, K=512) -> y0, y1 fp32 (+bo on kz=0)
  gemm256<0><<<dim3(256), dim3(512), 0, stream>>>(
      ctx, 1024, WoT, 1024, 512, 4, 128, 512, 512, (size_t)NTOK * 1024,
      bo, nullptr, nullptr, y0, nullptr, nullptr, 1024, 1.f);

  // LN1 -> hb (bf16)
  ln1_kernel<<<dim3(NTOK), dim3(256), 0, stream>>>(x, y0, y1, g1, be1, hb);

  // FFN1: M=8192, N=2048, K=1024 (grid 32x8 = 256) -> u bf16 relu
  gemm256<1><<<dim3(256), dim3(512), 0, stream>>>(
      hb, 1024, W1T, 1024, 1024, 8, 256, 0, 0, 0,
      b1, nullptr, nullptr, u, nullptr, nullptr, 2048, 1.f);

  // FFN2 split-K: 2 x (M=8192, N=1024, K=1024) -> y0, y1 fp32
  gemm256<0><<<dim3(256), dim3(512), 0, stream>>>(
      u, 2048, W2T, 2048, 1024, 4, 128, 1024, 1024, (size_t)NTOK * 1024,
      b2, nullptr, nullptr, y0, nullptr, nullptr, 1024, 1.f);

  // LN2 -> d_out
  ln2_kernel<<<dim3(NTOK), dim3(256), 0, stream>>>(hb, y0, y1, g2, be2, (float*)d_out);
}